// Round 2
// baseline (656.366 us; speedup 1.0000x reference)
//
#include <hip/hip_runtime.h>
#include <hip/hip_bf16.h>
#include <stdint.h>

#define D 1024
#define F 4096
#define E 8
#define T 8192
#define SLOT_CAP 18432   // 16384 routed slots + per-expert pad to 256
#define BM 128
#define BK 32
#define EP_STRIDE 136    // gemm2 epilogue LDS row stride (shorts)

// gemm1 256x256 tile params
#define BM2 256
#define BN2 256
#define BK2 32
#define EP2 268          // gemm1 epilogue stride (shorts)

typedef __attribute__((ext_vector_type(8))) short bf16x8;
typedef __attribute__((ext_vector_type(4))) float f32x4;
typedef __attribute__((ext_vector_type(8))) unsigned short u16x8;

__device__ __forceinline__ unsigned short f2bf(float f) {
  unsigned u = __float_as_uint(f);
  u += 0x7fffu + ((u >> 16) & 1u);
  return (unsigned short)(u >> 16);
}
__device__ __forceinline__ float bf2f(unsigned short u) {
  return __uint_as_float(((unsigned)u) << 16);
}

// exact-GELU via A&S 7.1.26 erf approx (|err| <= 1.5e-7), branch-free.
__device__ __forceinline__ float gelu_f(float v) {
  float s = fabsf(v) * 0.70710678118654752f;
  float t = __builtin_amdgcn_rcpf(fmaf(0.3275911f, s, 1.0f));
  float p = fmaf(t, 1.061405429f, -1.453152027f);
  p = fmaf(t, p, 1.421413741f);
  p = fmaf(t, p, -0.284496736f);
  p = fmaf(t, p, 0.254829592f);
  p = p * t;
  float e = 1.0f - p * __expf(-s * s);   // erf(|s|)
  e = copysignf(e, v);
  return 0.5f * v * (1.0f + e);
}

// global -> LDS async copy, 16B per lane. LDS dest must be wave-uniform base + lane*16.
__device__ __forceinline__ void gload16(const void* g, void* l) {
  auto gp = (const __attribute__((address_space(1))) unsigned int*)(uintptr_t)g;
  auto lp = (__attribute__((address_space(3))) unsigned int*)(unsigned)(uintptr_t)l;
  __builtin_amdgcn_global_load_lds(gp, lp, 16, 0, 0);
}

// Merged prep: blocks [0,2048) = router (1 wave/token, fp64 accumulate so top-2
// selection matches the fp32 reference; also emits bf16 x). Blocks [2048,34816) =
// fp32->bf16 weight casts. Independent work -> router hides under the cast stream.
__global__ __launch_bounds__(256) void prep_kernel(const float* __restrict__ x,
                                                   const float* __restrict__ rw,
                                                   const float* __restrict__ w1,
                                                   const float* __restrict__ w2,
                                                   int* __restrict__ tok_e,
                                                   float* __restrict__ tok_p,
                                                   unsigned short* __restrict__ xg,
                                                   unsigned short* __restrict__ w1g,
                                                   unsigned short* __restrict__ w2g) {
  if (blockIdx.x >= 2048) {
    const int n8 = E * F * D / 8;
    int i = (blockIdx.x - 2048) * 256 + threadIdx.x;
    const float* in = w1;
    unsigned short* out = w1g;
    if (i >= n8) { i -= n8; in = w2; out = w2g; }
    const float4* p = (const float4*)in + (size_t)i * 2;
    float4 a = p[0], b = p[1];
    u16x8 o;
    o[0] = f2bf(a.x); o[1] = f2bf(a.y); o[2] = f2bf(a.z); o[3] = f2bf(a.w);
    o[4] = f2bf(b.x); o[5] = f2bf(b.y); o[6] = f2bf(b.z); o[7] = f2bf(b.w);
    *(u16x8*)(out + (size_t)i * 8) = o;
    return;
  }
  int t = blockIdx.x * 4 + (threadIdx.x >> 6);
  int lane = threadIdx.x & 63;
  const float* xp = x + (size_t)t * D;
  unsigned short* xgp = xg + (size_t)t * D;
  double acc[E];
#pragma unroll
  for (int e = 0; e < E; e++) acc[e] = 0.0;
  for (int j = 0; j < D / 64; j++) {
    float xv = xp[j * 64 + lane];
    xgp[j * 64 + lane] = f2bf(xv);
#pragma unroll
    for (int e = 0; e < E; e++) acc[e] += (double)xv * (double)rw[e * D + j * 64 + lane];
  }
#pragma unroll
  for (int e = 0; e < E; e++) {
#pragma unroll
    for (int off = 32; off >= 1; off >>= 1) acc[e] += __shfl_xor(acc[e], off, 64);
  }
  if (lane == 0) {
    double v0 = -1e300, v1 = -1e300;
    int i0 = 0, i1 = 0;
#pragma unroll
    for (int e = 0; e < E; e++) {
      double v = acc[e];
      if (v > v0) { v1 = v0; i1 = i0; v0 = v; i0 = e; }
      else if (v > v1) { v1 = v; i1 = e; }
    }
    double e1 = exp(v1 - v0);
    double s = 1.0 + e1;
    tok_e[2 * t] = i0; tok_e[2 * t + 1] = i1;
    tok_p[2 * t] = (float)(1.0 / s);
    tok_p[2 * t + 1] = (float)(e1 / s);
  }
}

// Atomic-free bucketing: 8 blocks x 1 wave. Block e computes the full histogram
// (shfl-reduced), derives offp locally, then rank-scatters its expert's entries via
// ballot+popc (deterministic), zeroes its pad region. Block 0 publishes counts/offp.
// Pad granularity 256 (gemm1 256-row tiles; gemm2 128-row tiles divide it evenly).
__global__ __launch_bounds__(64) void bucket_kernel(const int* __restrict__ tok_e,
                                                    int* __restrict__ perm,
                                                    int* __restrict__ slot_of,
                                                    int* __restrict__ counts,
                                                    int* __restrict__ offp) {
  const int e = blockIdx.x;
  const int lane = threadIdx.x;
  int cnt[E];
#pragma unroll
  for (int ee = 0; ee < E; ee++) cnt[ee] = 0;
  for (int idx = lane; idx < 2 * T; idx += 64) {
    int v = tok_e[idx];
#pragma unroll
    for (int ee = 0; ee < E; ee++) cnt[ee] += (v == ee) ? 1 : 0;
  }
#pragma unroll
  for (int ee = 0; ee < E; ee++) {
#pragma unroll
    for (int off = 32; off >= 1; off >>= 1) cnt[ee] += __shfl_xor(cnt[ee], off, 64);
  }
  int off_e[E + 1];
  int o = 0;
#pragma unroll
  for (int ee = 0; ee < E; ee++) { off_e[ee] = o; o += (cnt[ee] + 255) & ~255; }
  off_e[E] = o;
  if (e == 0 && lane == 0) {
#pragma unroll
    for (int ee = 0; ee < E; ee++) { counts[ee] = cnt[ee]; offp[ee] = off_e[ee]; }
    offp[E] = o;
  }
  int base = 0, mycnt = 0, myend = 0;
#pragma unroll
  for (int ee = 0; ee < E; ee++) {
    if (ee == e) { base = off_e[ee]; mycnt = cnt[ee]; myend = off_e[ee + 1]; }
  }
  const int pad0 = base + mycnt;
  for (int r = 0; r < 2 * T / 64; r++) {
    int idx = r * 64 + lane;
    int v = tok_e[idx];
    bool m = (v == e);
    unsigned long long mask = __ballot(m);
    int pre = __popcll(mask & ((1ull << lane) - 1ull));
    if (m) {
      int slot = base + pre;
      perm[slot] = idx >> 1;
      slot_of[idx] = slot;
    }
    base += __popcll(mask);
  }
  for (int i = pad0 + lane; i < myend; i += 64) perm[i] = 0;
}

// GEMM1: hbuf[slot][f] = gelu( x[perm[slot]] . w1[e][f] + b1[e][f] ), bf16 out.
// 256x256 tile, 512 thr / 8 waves (2M x 4N), BK=32, ring-of-4 LDS K-tile buffers
// (128 KiB). Counted-vmcnt pipeline: while computing tile kt, stage kt+3 into
// buf[(kt+3)&3] (= buffer consumed at kt-1, race-free by barrier order); boundary
// wait is vmcnt(8) (2 tiles x 4 loads in flight), never 0 in the main loop.
//
// CONFLICT-FREE LDS LAYOUT (fix for R1's 1.34e7 bank conflicts): within each
// 16-row x 32-col bf16 subtile (1024B, 64 16B-slots), slot index
//   p = (r&7) + 8*(chunk + 4*((r>>3)&1))
// so a fragment read by lane (fr,fq) hits 16B-slot position s = fr&7: every
// aligned 8-lane group covers all 8 bank-quads bijectively -> 0 conflicts.
// LDS dest of global_load_lds stays LINEAR (HW constraint); the permutation is
// applied to the per-thread GLOBAL source (slot q -> row/chunk decode below).
__global__ __launch_bounds__(512, 2) void gemm1_kernel(const unsigned short* __restrict__ xg,
                                                       const unsigned short* __restrict__ w1g,
                                                       const float* __restrict__ b1,
                                                       const int* __restrict__ perm,
                                                       const int* __restrict__ offp,
                                                       const int* __restrict__ counts,
                                                       unsigned short* __restrict__ hbuf) {
  const int id = blockIdx.x;                    // grid 1152 = 8 XCD x 144; 72bm x 16bn
  const int swz = (id & 7) * 144 + (id >> 3);
  const int bm = swz >> 4, bn = swz & 15;
  const int row0 = bm * BM2;
  if (row0 >= offp[E]) return;
  int e = 0;
#pragma unroll
  for (int i = 0; i < E; i++) if (row0 >= offp[i + 1]) e = i + 1;
  if (row0 >= offp[e] + counts[e]) return;      // block entirely padding

  const int t = threadIdx.x, lane = t & 63, w = t >> 6;
  const int wm = w >> 2, wn = w & 3;            // wave tile: rows wm*128, cols wn*64
  const int fr = lane & 15, fq = lane >> 4;

  __shared__ __align__(16) unsigned short smem[65536];  // 128 KiB: 4 bufs x (A 16KB + B 16KB)

  // Staging decode: thread t owns 16B-slots q0=t, q1=512+t of the A region (and
  // the same q of the B region). Inverse of the subtile layout:
  //   st=q>>6, s=q&7, h=(q>>3)&7  ->  chunk c=h&3, row r = st*16 + (h>>2)*8 + s.
  int r0, c0, r1, c1;
  {
    int q = t;
    int s = q & 7, h = (q >> 3) & 7;
    c0 = h & 3; r0 = (q >> 6) * 16 + (h >> 2) * 8 + s;
    q = 512 + t;
    s = q & 7; h = (q >> 3) & 7;
    c1 = h & 3; r1 = (q >> 6) * 16 + (h >> 2) * 8 + s;
  }
  const unsigned short* srcA[2];
  const unsigned short* srcB[2];
  srcA[0] = xg + (size_t)perm[row0 + r0] * D + c0 * 8;
  srcA[1] = xg + (size_t)perm[row0 + r1] * D + c1 * 8;
  srcB[0] = w1g + ((size_t)e * F + (size_t)bn * BN2 + r0) * D + c0 * 8;
  srcB[1] = w1g + ((size_t)e * F + (size_t)bn * BN2 + r1) * D + c1 * 8;

  // Bias into registers, consumed NOW so no vmem op is outstanding when the
  // hand-counted vmcnt pipeline starts.
  float biasv[4];
#pragma unroll
  for (int n = 0; n < 4; n++) {
    biasv[n] = b1[e * F + bn * BN2 + wn * 64 + n * 16 + fr];
    asm volatile("" :: "v"(biasv[n]));
  }

  auto stageA = [&](int tk) {
    unsigned short* base = smem + (tk & 3) * 16384 + t * 8;
    gload16(srcA[0] + tk * 32, base);
    gload16(srcA[1] + tk * 32, base + 4096);
  };
  auto stageB = [&](int tk) {
    unsigned short* base = smem + (tk & 3) * 16384 + 8192 + t * 8;
    gload16(srcB[0] + tk * 32, base);
    gload16(srcB[1] + tk * 32, base + 4096);
  };

  // Per-lane ds_read offsets (shorts): subtile st * 512 + slot p * 8,
  // p = (fr&7) + 8*fq + 32*(fr>>3).
  const int pl = ((fr & 7) + 8 * fq + 32 * (fr >> 3)) * 8;
  int aoff[8], boff[4];
#pragma unroll
  for (int m = 0; m < 8; m++) aoff[m] = (wm * 8 + m) * 512 + pl;
#pragma unroll
  for (int n = 0; n < 4; n++) boff[n] = 8192 + (wn * 4 + n) * 512 + pl;

  f32x4 acc[8][4] = {};

  // Prologue: tiles 0,1,2 in flight (12 loads). vmcnt(8) -> tile 0 landed.
  stageA(0); stageB(0);
  stageA(1); stageB(1);
  stageA(2); stageB(2);
  asm volatile("s_waitcnt vmcnt(8)" ::: "memory");
  __builtin_amdgcn_s_barrier();
  __builtin_amdgcn_sched_barrier(0);

  const int NK = D / BK2;   // 32
#pragma unroll 4
  for (int kt = 0; kt < NK; ++kt) {
    const unsigned short* tb = smem + (kt & 3) * 16384;
    // phase 0: A rows 0..63 of wave tile + all B, stage A of kt+3, 16 MFMA
    bf16x8 a0[4], b[4];
#pragma unroll
    for (int m = 0; m < 4; m++) a0[m] = *(const bf16x8*)(tb + aoff[m]);
#pragma unroll
    for (int n = 0; n < 4; n++) b[n] = *(const bf16x8*)(tb + boff[n]);
    if (kt + 3 < NK) stageA(kt + 3);
    __builtin_amdgcn_s_setprio(1);
#pragma unroll
    for (int m = 0; m < 4; m++)
#pragma unroll
      for (int n = 0; n < 4; n++)
        acc[m][n] = __builtin_amdgcn_mfma_f32_16x16x32_bf16(a0[m], b[n], acc[m][n], 0, 0, 0);
    __builtin_amdgcn_s_setprio(0);
    __builtin_amdgcn_s_barrier();
    __builtin_amdgcn_sched_barrier(0);
    // phase 1: A rows 64..127, stage B of kt+3, 16 MFMA
    bf16x8 a1[4];
#pragma unroll
    for (int m = 0; m < 4; m++) a1[m] = *(const bf16x8*)(tb + aoff[4 + m]);
    if (kt + 3 < NK) stageB(kt + 3);
    __builtin_amdgcn_s_setprio(1);
#pragma unroll
    for (int m = 0; m < 4; m++)
#pragma unroll
      for (int n = 0; n < 4; n++)
        acc[4 + m][n] = __builtin_amdgcn_mfma_f32_16x16x32_bf16(a1[m], b[n], acc[4 + m][n], 0, 0, 0);
    __builtin_amdgcn_s_setprio(0);
    // Boundary wait: next tile (kt+1) fully landed. Steady state vmcnt(8)
    // (= tiles kt+2,kt+3 in flight); drain 8->4->0 over the last 3 tiles.
    if (kt < NK - 3)       { asm volatile("s_waitcnt vmcnt(8)" ::: "memory"); }
    else if (kt == NK - 3) { asm volatile("s_waitcnt vmcnt(4)" ::: "memory"); }
    else if (kt == NK - 2) { asm volatile("s_waitcnt vmcnt(0)" ::: "memory"); }
    __builtin_amdgcn_s_barrier();
    __builtin_amdgcn_sched_barrier(0);
  }

  // Epilogue: bias+gelu in-register -> bf16 LDS half-tile (stride EP2) ->
  // coalesced 16B/lane stores. Two passes (rows 0..127, 128..255) to fit LDS.
  __syncthreads();
  unsigned short* ep = smem;
#pragma unroll
  for (int p = 0; p < 2; p++) {
    if (wm == p) {
#pragma unroll
      for (int n = 0; n < 4; n++) {
        int col = wn * 64 + n * 16 + fr;
#pragma unroll
        for (int m = 0; m < 8; m++) {
#pragma unroll
          for (int j = 0; j < 4; j++) {
            int lr = m * 16 + fq * 4 + j;
            ep[lr * EP2 + col] = f2bf(gelu_f(acc[m][n][j] + biasv[n]));
          }
        }
      }
    }
    __syncthreads();
#pragma unroll
    for (int i = 0; i < 8; i++) {
      int idx = t + i * 512;            // 4096 chunks: 128 rows x 32
      int r2 = idx >> 5, c8 = (idx & 31) * 8;
      u16x8 v = *(const u16x8*)&ep[r2 * EP2 + c8];
      *(u16x8*)&hbuf[(size_t)(row0 + p * 128 + r2) * F + (size_t)bn * BN2 + c8] = v;
    }
    __syncthreads();
  }
}

// GEMM2 (K-split-2): ypart[ks][slot][d] = h[slot][ks*2048:+2048].w2[e][d][same] (+b2 if ks==0)
// 128x128 tile, dbuf, 3 blocks/CU. Grid 2304 = 8 XCD x 288 (144bm x 8bn x 2ks).
__global__ __launch_bounds__(256, 3) void gemm2_kernel(const unsigned short* __restrict__ hbuf,
                                                       const unsigned short* __restrict__ w2g,
                                                       const float* __restrict__ b2,
                                                       const int* __restrict__ offp,
                                                       const int* __restrict__ counts,
                                                       unsigned short* __restrict__ ypart) {
  const int id = blockIdx.x;
  const int swz = (id & 7) * 288 + (id >> 3);   // bijective (2304=8*288)
  const int bn = swz & 7;                        // bn fastest -> share A panel
  const int ks = (swz >> 3) & 1;
  const int bm = swz >> 4;
  const int row0 = bm * BM;
  if (row0 >= offp[E]) return;
  int e = 0;
#pragma unroll
  for (int i = 0; i < E; i++) if (row0 >= offp[i + 1]) e = i + 1;
  const int valid_end = offp[e] + counts[e];
  if (row0 >= valid_end) return;

  const int tid = threadIdx.x, lane = tid & 63, w = tid >> 6;
  __shared__ __align__(16) unsigned short smem[BM * EP_STRIDE];
  unsigned short* As0 = smem;
  unsigned short* Bs0 = smem + 8192;

  const int kbase = ks * (F / 2);
  const unsigned short* gsrc[4];
  unsigned short* ldst[4];
#pragma unroll
  for (int i = 0; i < 4; i++) {
    int ch = tid + 256 * i;
    if (ch < 512) {
      int ar = ch >> 2, ac = (ch & 3) * 8;
      gsrc[i] = hbuf + (size_t)(row0 + ar) * F + kbase + ac;
      ldst[i] = As0 + ch * 8;
    } else {
      int c = ch - 512;
      int br = c >> 2, bc = (c & 3) * 8;
      gsrc[i] = w2g + ((size_t)e * D + (size_t)bn * BM + br) * F + kbase + bc;
      ldst[i] = Bs0 + c * 8;
    }
  }
  auto stage = [&](int k0, int buf) {
#pragma unroll
    for (int i = 0; i < 4; i++) gload16(gsrc[i] + k0, ldst[i] + buf * (BM * BK));
  };

  f32x4 acc[4][4] = {};
  const int wr = (w >> 1) * 64, wc = (w & 1) * 64;
  const int fr = lane & 15, fq = lane >> 4;

  stage(0, 0);
  __syncthreads();
  int cur = 0;
  for (int k0 = 0; k0 < F / 2; k0 += BK) {
    if (k0 + BK < F / 2) stage(k0 + BK, cur ^ 1);
    bf16x8 a[4], b[4];
#pragma unroll
    for (int m = 0; m < 4; m++) a[m] = *(const bf16x8*)&As0[cur * 4096 + (wr + m * 16 + fr) * BK + fq * 8];
#pragma unroll
    for (int n = 0; n < 4; n++) b[n] = *(const bf16x8*)&Bs0[cur * 4096 + (wc + n * 16 + fr) * BK + fq * 8];
#pragma unroll
    for (int m = 0; m < 4; m++)
#pragma unroll
      for (int n = 0; n < 4; n++)
        acc[m][n] = __builtin_amdgcn_mfma_f32_16x16x32_bf16(a[m], b[n], acc[m][n], 0, 0, 0);
    __syncthreads();
    cur ^= 1;
  }

  // epilogue via LDS (full-line coalesced stores)
#pragma unroll
  for (int n = 0; n < 4; n++) {
    int cl = wc + n * 16 + fr;
    float bias = (ks == 0) ? b2[e * D + bn * BM + cl] : 0.0f;
#pragma unroll
    for (int m = 0; m < 4; m++) {
#pragma unroll
      for (int j = 0; j < 4; j++) {
        int rl = wr + m * 16 + fq * 4 + j;
        smem[rl * EP_STRIDE + cl] = f2bf(acc[m][n][j] + bias);
      }
    }
  }
  __syncthreads();
  unsigned short* ybase = ypart + (size_t)ks * SLOT_CAP * D;
#pragma unroll
  for (int i = 0; i < 8; i++) {
    int idx = tid + i * 256;
    int r2 = idx >> 4, c = (idx & 15) * 8;
    if (row0 + r2 < valid_end) {
      u16x8 v = *(const u16x8*)&smem[r2 * EP_STRIDE + c];
      *(u16x8*)&ybase[(size_t)(row0 + r2) * D + bn * BM + c] = v;
    }
  }
}

// out[t][d] = g0*(p0[s0]+p1[s0]) + g1*(p0[s1]+p1[s1])   (full overwrite -> no memset)
__global__ __launch_bounds__(256) void combine_kernel(const unsigned short* __restrict__ ypart,
                                                      const int* __restrict__ slot_of,
                                                      const float* __restrict__ tok_p,
                                                      float* __restrict__ out) {
  int i = blockIdx.x * 256 + threadIdx.x;   // indexes 8-elem groups
  int t = i >> 7;                            // D/8 = 128 groups per token
  int g8 = i & 127;
  int s0 = slot_of[2 * t], s1 = slot_of[2 * t + 1];
  float g0 = tok_p[2 * t], g1 = tok_p[2 * t + 1];
  const unsigned short* p0 = ypart;
  const unsigned short* p1 = ypart + (size_t)SLOT_CAP * D;
  u16x8 a0 = *(const u16x8*)(p0 + (size_t)s0 * D + g8 * 8);
  u16x8 b0 = *(const u16x8*)(p1 + (size_t)s0 * D + g8 * 8);
  u16x8 a1 = *(const u16x8*)(p0 + (size_t)s1 * D + g8 * 8);
  u16x8 b1 = *(const u16x8*)(p1 + (size_t)s1 * D + g8 * 8);
  float o[8];
#pragma unroll
  for (int j = 0; j < 8; j++)
    o[j] = g0 * (bf2f(a0[j]) + bf2f(b0[j])) + g1 * (bf2f(a1[j]) + bf2f(b1[j]));
  float4* op = (float4*)(out + (size_t)t * D + g8 * 8);
  op[0] = make_float4(o[0], o[1], o[2], o[3]);
  op[1] = make_float4(o[4], o[5], o[6], o[7]);
}

extern "C" void kernel_launch(void* const* d_in, const int* in_sizes, int n_in,
                              void* d_out, int out_size, void* d_ws, size_t ws_size,
                              hipStream_t stream) {
  const float* x = (const float*)d_in[0];
  const float* rw = (const float*)d_in[1];
  const float* w1 = (const float*)d_in[2];
  const float* b1 = (const float*)d_in[3];
  const float* w2 = (const float*)d_in[4];
  const float* b2 = (const float*)d_in[5];
  float* out = (float*)d_out;

  char* ws = (char*)d_ws;
  size_t off = 0;
  auto alloc = [&](size_t bytes) {
    void* p = ws + off;
    off = (off + bytes + 255) & ~(size_t)255;
    return p;
  };
  int* counts = (int*)alloc(E * 4);
  int* offp = (int*)alloc((E + 1) * 4);
  int* tok_e = (int*)alloc((size_t)T * 2 * 4);
  float* tok_p = (float*)alloc((size_t)T * 2 * 4);
  int* perm = (int*)alloc((size_t)SLOT_CAP * 4);
  int* slot_of = (int*)alloc((size_t)T * 2 * 4);
  unsigned short* xg = (unsigned short*)alloc((size_t)T * D * 2);        // 16.8 MB
  unsigned short* w1g = (unsigned short*)alloc((size_t)E * F * D * 2);   // 67 MB
  unsigned short* w2g = (unsigned short*)alloc((size_t)E * D * F * 2);   // 67 MB
  unsigned short* hbuf = (unsigned short*)alloc((size_t)SLOT_CAP * F * 2); // 151 MB
  // ypart: 2 bf16 partial buffers, 75.5 MB, aliased over xg(16.8)+w1g(67)
  // (dead after gemm1; re-written by prep every call -> deterministic).
  unsigned short* ypart = xg;
  (void)ws_size; (void)in_sizes; (void)n_in; (void)out_size;

  hipLaunchKernelGGL(prep_kernel, dim3(2048 + 2 * E * F * D / 8 / 256), dim3(256), 0, stream,
                     x, rw, w1, w2, tok_e, tok_p, xg, w1g, w2g);
  hipLaunchKernelGGL(bucket_kernel, dim3(E), dim3(64), 0, stream,
                     tok_e, perm, slot_of, counts, offp);
  hipLaunchKernelGGL(gemm1_kernel, dim3(1152), dim3(512), 0, stream,
                     xg, w1g, b1, perm, offp, counts, hbuf);
  hipLaunchKernelGGL(gemm2_kernel, dim3(2304), dim3(256), 0, stream,
                     hbuf, w2g, b2, offp, counts, ypart);
  hipLaunchKernelGGL(combine_kernel, dim3(T * D / 8 / 256), dim3(256), 0, stream,
                     ypart, slot_of, tok_p, out);
}

// Round 3
// 561.691 us; speedup vs baseline: 1.1686x; 1.1686x over previous
//
#include <hip/hip_runtime.h>
#include <hip/hip_bf16.h>
#include <stdint.h>

#define D 1024
#define F 4096
#define E 8
#define T 8192
#define SLOT_CAP 17408   // 16384 routed slots + per-expert pad to 128
#define BM 128
#define BK 32
#define EP_STRIDE 136    // epilogue LDS row stride (shorts): +8 pad kills bank conflicts

typedef __attribute__((ext_vector_type(8))) short bf16x8;
typedef __attribute__((ext_vector_type(4))) float f32x4;
typedef __attribute__((ext_vector_type(8))) unsigned short u16x8;

__device__ __forceinline__ unsigned short f2bf(float f) {
  unsigned u = __float_as_uint(f);
  u += 0x7fffu + ((u >> 16) & 1u);
  return (unsigned short)(u >> 16);
}
__device__ __forceinline__ float bf2f(unsigned short u) {
  return __uint_as_float(((unsigned)u) << 16);
}

// exact-GELU via A&S 7.1.26 erf approx (|err| <= 1.5e-7), branch-free.
__device__ __forceinline__ float gelu_f(float v) {
  float s = fabsf(v) * 0.70710678118654752f;
  float t = __builtin_amdgcn_rcpf(fmaf(0.3275911f, s, 1.0f));
  float p = fmaf(t, 1.061405429f, -1.453152027f);
  p = fmaf(t, p, 1.421413741f);
  p = fmaf(t, p, -0.284496736f);
  p = fmaf(t, p, 0.254829592f);
  p = p * t;
  float e = 1.0f - p * __expf(-s * s);   // erf(|s|)
  e = copysignf(e, v);
  return 0.5f * v * (1.0f + e);
}

// global -> LDS async copy, 16B per lane. LDS dest must be wave-uniform base + lane*16.
__device__ __forceinline__ void gload16(const void* g, void* l) {
  auto gp = (const __attribute__((address_space(1))) unsigned int*)(uintptr_t)g;
  auto lp = (__attribute__((address_space(3))) unsigned int*)(unsigned)(uintptr_t)l;
  __builtin_amdgcn_global_load_lds(gp, lp, 16, 0, 0);
}

// Merged prep: blocks [0,2048) = router (1 wave/token, fp64 accumulate so top-2
// selection matches the fp32 reference; also emits bf16 x). Blocks [2048,18432) =
// fp32->bf16 cast of w1 ONLY. The w2 cast is deferred into gemm1's launch (it is
// not needed until gemm2) so its ~200 MB of traffic hides under gemm1 compute.
__global__ __launch_bounds__(256) void prep_kernel(const float* __restrict__ x,
                                                   const float* __restrict__ rw,
                                                   const float* __restrict__ w1,
                                                   int* __restrict__ tok_e,
                                                   float* __restrict__ tok_p,
                                                   unsigned short* __restrict__ xg,
                                                   unsigned short* __restrict__ w1g) {
  if (blockIdx.x >= 2048) {
    int i = (blockIdx.x - 2048) * 256 + threadIdx.x;   // [0, E*F*D/8)
    const float4* p = (const float4*)w1 + (size_t)i * 2;
    float4 a = p[0], b = p[1];
    u16x8 o;
    o[0] = f2bf(a.x); o[1] = f2bf(a.y); o[2] = f2bf(a.z); o[3] = f2bf(a.w);
    o[4] = f2bf(b.x); o[5] = f2bf(b.y); o[6] = f2bf(b.z); o[7] = f2bf(b.w);
    *(u16x8*)(w1g + (size_t)i * 8) = o;
    return;
  }
  int t = blockIdx.x * 4 + (threadIdx.x >> 6);
  int lane = threadIdx.x & 63;
  const float* xp = x + (size_t)t * D;
  unsigned short* xgp = xg + (size_t)t * D;
  double acc[E];
#pragma unroll
  for (int e = 0; e < E; e++) acc[e] = 0.0;
  for (int j = 0; j < D / 64; j++) {
    float xv = xp[j * 64 + lane];
    xgp[j * 64 + lane] = f2bf(xv);
#pragma unroll
    for (int e = 0; e < E; e++) acc[e] += (double)xv * (double)rw[e * D + j * 64 + lane];
  }
#pragma unroll
  for (int e = 0; e < E; e++) {
#pragma unroll
    for (int off = 32; off >= 1; off >>= 1) acc[e] += __shfl_xor(acc[e], off, 64);
  }
  if (lane == 0) {
    double v0 = -1e300, v1 = -1e300;
    int i0 = 0, i1 = 0;
#pragma unroll
    for (int e = 0; e < E; e++) {
      double v = acc[e];
      if (v > v0) { v1 = v0; i1 = i0; v0 = v; i0 = e; }
      else if (v > v1) { v1 = v; i1 = e; }
    }
    double e1 = exp(v1 - v0);
    double s = 1.0 + e1;
    tok_e[2 * t] = i0; tok_e[2 * t + 1] = i1;
    tok_p[2 * t] = (float)(1.0 / s);
    tok_p[2 * t + 1] = (float)(e1 / s);
  }
}

// Atomic-free bucketing: 8 blocks x 1 wave. Block e computes the full histogram
// (shfl-reduced), derives offp locally, then rank-scatters its expert's entries via
// ballot+popc (deterministic), zeroes its pad region. Block 0 publishes counts/offp.
__global__ __launch_bounds__(64) void bucket_kernel(const int* __restrict__ tok_e,
                                                    int* __restrict__ perm,
                                                    int* __restrict__ slot_of,
                                                    int* __restrict__ counts,
                                                    int* __restrict__ offp) {
  const int e = blockIdx.x;
  const int lane = threadIdx.x;
  int cnt[E];
#pragma unroll
  for (int ee = 0; ee < E; ee++) cnt[ee] = 0;
  for (int idx = lane; idx < 2 * T; idx += 64) {
    int v = tok_e[idx];
#pragma unroll
    for (int ee = 0; ee < E; ee++) cnt[ee] += (v == ee) ? 1 : 0;
  }
#pragma unroll
  for (int ee = 0; ee < E; ee++) {
#pragma unroll
    for (int off = 32; off >= 1; off >>= 1) cnt[ee] += __shfl_xor(cnt[ee], off, 64);
  }
  int off_e[E + 1];
  int o = 0;
#pragma unroll
  for (int ee = 0; ee < E; ee++) { off_e[ee] = o; o += (cnt[ee] + (BM - 1)) & ~(BM - 1); }
  off_e[E] = o;
  if (e == 0 && lane == 0) {
#pragma unroll
    for (int ee = 0; ee < E; ee++) { counts[ee] = cnt[ee]; offp[ee] = off_e[ee]; }
    offp[E] = o;
  }
  int base = 0, mycnt = 0, myend = 0;
#pragma unroll
  for (int ee = 0; ee < E; ee++) {
    if (ee == e) { base = off_e[ee]; mycnt = cnt[ee]; myend = off_e[ee + 1]; }
  }
  const int pad0 = base + mycnt;
  for (int r = 0; r < 2 * T / 64; r++) {
    int idx = r * 64 + lane;
    int v = tok_e[idx];
    bool m = (v == e);
    unsigned long long mask = __ballot(m);
    int pre = __popcll(mask & ((1ull << lane) - 1ull));
    if (m) {
      int slot = base + pre;
      perm[slot] = idx >> 1;
      slot_of[idx] = slot;
    }
    base += __popcll(mask);
  }
  for (int i = pad0 + lane; i < myend; i += 64) perm[i] = 0;
}

// GEMM1: hbuf[slot][f] = gelu( x[perm[slot]] . w1[e][f] + b1[e][f] ), bf16 out
// 128x128 tile, dbuf, 3 blocks/CU. XCD-chunked (8 x 544) quarter-walk (R11-measured).
// Blocks [4352, 20736): fp32->bf16 cast of w2 (backfills free CU slots while the
// compute blocks run; gemm1 uses ~1.4 of 6.3 TB/s, so the cast traffic hides).
__global__ __launch_bounds__(256, 3) void gemm1_kernel(const unsigned short* __restrict__ xg,
                                                       const unsigned short* __restrict__ w1g,
                                                       const float* __restrict__ b1,
                                                       const int* __restrict__ perm,
                                                       const int* __restrict__ offp,
                                                       const int* __restrict__ counts,
                                                       unsigned short* __restrict__ hbuf,
                                                       const float* __restrict__ w2,
                                                       unsigned short* __restrict__ w2g) {
  const int id = blockIdx.x;
  if (id >= 4352) {                              // trailing w2-cast blocks
    int i = (id - 4352) * 256 + threadIdx.x;     // [0, E*D*F/8)
    const float4* p = (const float4*)w2 + (size_t)i * 2;
    float4 a = p[0], b = p[1];
    u16x8 o;
    o[0] = f2bf(a.x); o[1] = f2bf(a.y); o[2] = f2bf(a.z); o[3] = f2bf(a.w);
    o[4] = f2bf(b.x); o[5] = f2bf(b.y); o[6] = f2bf(b.z); o[7] = f2bf(b.w);
    *(u16x8*)(w2g + (size_t)i * 8) = o;
    return;
  }
  const int xcd = id & 7, loc = id >> 3;        // loc in [0,544)
  const int q = loc / 136, r = loc % 136;       // 4 quarters x (17bm x 8bn)
  const int bm = xcd * 17 + (r >> 3);
  const int bn = q * 8 + (r & 7);
  const int row0 = bm * BM;
  if (row0 >= offp[E]) return;
  int e = 0;
#pragma unroll
  for (int i = 0; i < E; i++) if (row0 >= offp[i + 1]) e = i + 1;
  if (row0 >= offp[e] + counts[e]) return;  // block entirely padding

  const int tid = threadIdx.x, lane = tid & 63, w = tid >> 6;
  __shared__ __align__(16) unsigned short smem[BM * EP_STRIDE];
  unsigned short* As0 = smem;            // As[buf] = As0 + buf*4096
  unsigned short* Bs0 = smem + 8192;     // Bs[buf] = Bs0 + buf*4096

  const unsigned short* gsrc[4];
  unsigned short* ldst[4];
#pragma unroll
  for (int i = 0; i < 4; i++) {
    int ch = tid + 256 * i;
    if (ch < 512) {
      int ar = ch >> 2, ac = (ch & 3) * 8;
      gsrc[i] = xg + (size_t)perm[row0 + ar] * D + ac;
      ldst[i] = As0 + ch * 8;
    } else {
      int c = ch - 512;
      int br = c >> 2, bc = (c & 3) * 8;
      gsrc[i] = w1g + ((size_t)e * F + (size_t)bn * BM + br) * D + bc;
      ldst[i] = Bs0 + c * 8;
    }
  }
  auto stage = [&](int k0, int buf) {
#pragma unroll
    for (int i = 0; i < 4; i++) gload16(gsrc[i] + k0, ldst[i] + buf * (BM * BK));
  };

  f32x4 acc[4][4] = {};
  const int wr = (w >> 1) * 64, wc = (w & 1) * 64;
  const int fr = lane & 15, fq = lane >> 4;

  stage(0, 0);
  __syncthreads();
  int cur = 0;
  for (int k0 = 0; k0 < D; k0 += BK) {
    if (k0 + BK < D) stage(k0 + BK, cur ^ 1);   // prefetch flies during compute
    bf16x8 a[4], b[4];
#pragma unroll
    for (int m = 0; m < 4; m++) a[m] = *(const bf16x8*)&As0[cur * 4096 + (wr + m * 16 + fr) * BK + fq * 8];
#pragma unroll
    for (int n = 0; n < 4; n++) b[n] = *(const bf16x8*)&Bs0[cur * 4096 + (wc + n * 16 + fr) * BK + fq * 8];
#pragma unroll
    for (int m = 0; m < 4; m++)
#pragma unroll
      for (int n = 0; n < 4; n++)
        acc[m][n] = __builtin_amdgcn_mfma_f32_16x16x32_bf16(a[m], b[n], acc[m][n], 0, 0, 0);
    __syncthreads();
    cur ^= 1;
  }

  // epilogue: bias+gelu in-register -> bf16 LDS tile -> coalesced 16B/lane stores
#pragma unroll
  for (int n = 0; n < 4; n++) {
    int cl = wc + n * 16 + fr;
    float bias = b1[e * F + bn * BM + cl];
#pragma unroll
    for (int m = 0; m < 4; m++) {
#pragma unroll
      for (int j = 0; j < 4; j++) {
        int rl = wr + m * 16 + fq * 4 + j;
        smem[rl * EP_STRIDE + cl] = f2bf(gelu_f(acc[m][n][j] + bias));
      }
    }
  }
  __syncthreads();
#pragma unroll
  for (int i = 0; i < 8; i++) {
    int idx = tid + i * 256;          // 2048 16B-chunks: 128 rows x 16
    int r2 = idx >> 4, c = (idx & 15) * 8;
    u16x8 v = *(const u16x8*)&smem[r2 * EP_STRIDE + c];
    *(u16x8*)&hbuf[(size_t)(row0 + r2) * F + bn * BM + c] = v;
  }
}

// GEMM2 (K-split-2): ypart[ks][slot][d] = h[slot][ks*2048:+2048].w2[e][d][same] (+b2 if ks==0)
// 128x128 tile, dbuf, 3 blocks/CU. Grid 2176 = 8bn x 2ks x 136bm = 8*272.
__global__ __launch_bounds__(256, 3) void gemm2_kernel(const unsigned short* __restrict__ hbuf,
                                                       const unsigned short* __restrict__ w2g,
                                                       const float* __restrict__ b2,
                                                       const int* __restrict__ offp,
                                                       const int* __restrict__ counts,
                                                       unsigned short* __restrict__ ypart) {
  const int id = blockIdx.x;
  const int swz = (id & 7) * 272 + (id >> 3);   // bijective (2176=8*272)
  const int bn = swz & 7;                        // bn fastest -> share A panel
  const int ks = (swz >> 3) & 1;
  const int bm = swz >> 4;
  const int row0 = bm * BM;
  if (row0 >= offp[E]) return;
  int e = 0;
#pragma unroll
  for (int i = 0; i < E; i++) if (row0 >= offp[i + 1]) e = i + 1;
  const int valid_end = offp[e] + counts[e];
  if (row0 >= valid_end) return;

  const int tid = threadIdx.x, lane = tid & 63, w = tid >> 6;
  __shared__ __align__(16) unsigned short smem[BM * EP_STRIDE];
  unsigned short* As0 = smem;
  unsigned short* Bs0 = smem + 8192;

  const int kbase = ks * (F / 2);
  const unsigned short* gsrc[4];
  unsigned short* ldst[4];
#pragma unroll
  for (int i = 0; i < 4; i++) {
    int ch = tid + 256 * i;
    if (ch < 512) {
      int ar = ch >> 2, ac = (ch & 3) * 8;
      gsrc[i] = hbuf + (size_t)(row0 + ar) * F + kbase + ac;
      ldst[i] = As0 + ch * 8;
    } else {
      int c = ch - 512;
      int br = c >> 2, bc = (c & 3) * 8;
      gsrc[i] = w2g + ((size_t)e * D + (size_t)bn * BM + br) * F + kbase + bc;
      ldst[i] = Bs0 + c * 8;
    }
  }
  auto stage = [&](int k0, int buf) {
#pragma unroll
    for (int i = 0; i < 4; i++) gload16(gsrc[i] + k0, ldst[i] + buf * (BM * BK));
  };

  f32x4 acc[4][4] = {};
  const int wr = (w >> 1) * 64, wc = (w & 1) * 64;
  const int fr = lane & 15, fq = lane >> 4;

  stage(0, 0);
  __syncthreads();
  int cur = 0;
  for (int k0 = 0; k0 < F / 2; k0 += BK) {
    if (k0 + BK < F / 2) stage(k0 + BK, cur ^ 1);
    bf16x8 a[4], b[4];
#pragma unroll
    for (int m = 0; m < 4; m++) a[m] = *(const bf16x8*)&As0[cur * 4096 + (wr + m * 16 + fr) * BK + fq * 8];
#pragma unroll
    for (int n = 0; n < 4; n++) b[n] = *(const bf16x8*)&Bs0[cur * 4096 + (wc + n * 16 + fr) * BK + fq * 8];
#pragma unroll
    for (int m = 0; m < 4; m++)
#pragma unroll
      for (int n = 0; n < 4; n++)
        acc[m][n] = __builtin_amdgcn_mfma_f32_16x16x32_bf16(a[m], b[n], acc[m][n], 0, 0, 0);
    __syncthreads();
    cur ^= 1;
  }

  // epilogue via LDS (full-line coalesced stores)
#pragma unroll
  for (int n = 0; n < 4; n++) {
    int cl = wc + n * 16 + fr;
    float bias = (ks == 0) ? b2[e * D + bn * BM + cl] : 0.0f;
#pragma unroll
    for (int m = 0; m < 4; m++) {
#pragma unroll
      for (int j = 0; j < 4; j++) {
        int rl = wr + m * 16 + fq * 4 + j;
        smem[rl * EP_STRIDE + cl] = f2bf(acc[m][n][j] + bias);
      }
    }
  }
  __syncthreads();
  unsigned short* ybase = ypart + (size_t)ks * SLOT_CAP * D;
#pragma unroll
  for (int i = 0; i < 8; i++) {
    int idx = tid + i * 256;
    int r2 = idx >> 4, c = (idx & 15) * 8;
    if (row0 + r2 < valid_end) {
      u16x8 v = *(const u16x8*)&smem[r2 * EP_STRIDE + c];
      *(u16x8*)&ybase[(size_t)(row0 + r2) * D + bn * BM + c] = v;
    }
  }
}

// out[t][d] = g0*(p0[s0]+p1[s0]) + g1*(p0[s1]+p1[s1])   (full overwrite -> no memset)
__global__ __launch_bounds__(256) void combine_kernel(const unsigned short* __restrict__ ypart,
                                                      const int* __restrict__ slot_of,
                                                      const float* __restrict__ tok_p,
                                                      float* __restrict__ out) {
  int i = blockIdx.x * 256 + threadIdx.x;   // indexes 8-elem groups
  int t = i >> 7;                            // D/8 = 128 groups per token
  int g8 = i & 127;
  int s0 = slot_of[2 * t], s1 = slot_of[2 * t + 1];
  float g0 = tok_p[2 * t], g1 = tok_p[2 * t + 1];
  const unsigned short* p0 = ypart;
  const unsigned short* p1 = ypart + (size_t)SLOT_CAP * D;
  u16x8 a0 = *(const u16x8*)(p0 + (size_t)s0 * D + g8 * 8);
  u16x8 b0 = *(const u16x8*)(p1 + (size_t)s0 * D + g8 * 8);
  u16x8 a1 = *(const u16x8*)(p0 + (size_t)s1 * D + g8 * 8);
  u16x8 b1 = *(const u16x8*)(p1 + (size_t)s1 * D + g8 * 8);
  float o[8];
#pragma unroll
  for (int j = 0; j < 8; j++)
    o[j] = g0 * (bf2f(a0[j]) + bf2f(b0[j])) + g1 * (bf2f(a1[j]) + bf2f(b1[j]));
  float4* op = (float4*)(out + (size_t)t * D + g8 * 8);
  op[0] = make_float4(o[0], o[1], o[2], o[3]);
  op[1] = make_float4(o[4], o[5], o[6], o[7]);
}

extern "C" void kernel_launch(void* const* d_in, const int* in_sizes, int n_in,
                              void* d_out, int out_size, void* d_ws, size_t ws_size,
                              hipStream_t stream) {
  const float* x = (const float*)d_in[0];
  const float* rw = (const float*)d_in[1];
  const float* w1 = (const float*)d_in[2];
  const float* b1 = (const float*)d_in[3];
  const float* w2 = (const float*)d_in[4];
  const float* b2 = (const float*)d_in[5];
  float* out = (float*)d_out;

  char* ws = (char*)d_ws;
  size_t off = 0;
  auto alloc = [&](size_t bytes) {
    void* p = ws + off;
    off = (off + bytes + 255) & ~(size_t)255;
    return p;
  };
  int* counts = (int*)alloc(E * 4);
  int* offp = (int*)alloc((E + 1) * 4);
  int* tok_e = (int*)alloc((size_t)T * 2 * 4);
  float* tok_p = (float*)alloc((size_t)T * 2 * 4);
  int* perm = (int*)alloc((size_t)SLOT_CAP * 4);
  int* slot_of = (int*)alloc((size_t)T * 2 * 4);
  unsigned short* xg = (unsigned short*)alloc((size_t)T * D * 2);        // 16.8 MB
  unsigned short* w1g = (unsigned short*)alloc((size_t)E * F * D * 2);   // 67 MB
  unsigned short* w2g = (unsigned short*)alloc((size_t)E * D * F * 2);   // 67 MB
  unsigned short* hbuf = (unsigned short*)alloc((size_t)SLOT_CAP * F * 2); // 143 MB
  // ypart: 2 bf16 partial buffers, 71.3 MB, aliased over xg(16.8)+w1g(67)
  // (dead after gemm1; re-written by prep every call -> deterministic).
  unsigned short* ypart = xg;
  (void)ws_size; (void)in_sizes; (void)n_in; (void)out_size;

  hipLaunchKernelGGL(prep_kernel, dim3(2048 + E * F * D / 8 / 256), dim3(256), 0, stream,
                     x, rw, w1, tok_e, tok_p, xg, w1g);
  hipLaunchKernelGGL(bucket_kernel, dim3(E), dim3(64), 0, stream,
                     tok_e, perm, slot_of, counts, offp);
  hipLaunchKernelGGL(gemm1_kernel, dim3(4352 + E * D * F / 8 / 256), dim3(256), 0, stream,
                     xg, w1g, b1, perm, offp, counts, hbuf, w2, w2g);
  hipLaunchKernelGGL(gemm2_kernel, dim3(2176), dim3(256), 0, stream,
                     hbuf, w2g, b2, offp, counts, ypart);
  hipLaunchKernelGGL(combine_kernel, dim3(T * D / 8 / 256), dim3(256), 0, stream,
                     ypart, slot_of, tok_p, out);
}